// Round 6
// baseline (451.930 us; speedup 1.0000x reference)
//
#include <hip/hip_runtime.h>
#include <math.h>

#define NROWS 6144
#define LSIG  5000
#define NT    256

// db4 decomposition filters (natural order), hi[k] = (-1)^(k+1) lo[k]
#define DL0 (-0.010597401784997278f)
#define DL1 ( 0.032883011666982945f)
#define DL2 ( 0.030841381835986965f)
#define DL3 (-0.18703481171888114f)
#define DL4 (-0.02798376941698385f)
#define DL5 ( 0.6308807679295904f)
#define DL6 ( 0.7148465705525415f)
#define DL7 ( 0.23037781330885523f)
#define DH0 ( 0.010597401784997278f)
#define DH1 ( 0.032883011666982945f)
#define DH2 (-0.030841381835986965f)
#define DH3 (-0.18703481171888114f)
#define DH4 ( 0.02798376941698385f)
#define DH5 ( 0.6308807679295904f)
#define DH6 (-0.7148465705525415f)
#define DH7 ( 0.23037781330885523f)

// Forward DWT (edge path): ca[k] = sum_t xp[2k+t]*lo[7-t].
// xp index map (reflect pad 7,7 drop first): j=2k+t-6; i=|j|; if i>=L -> 2L-2-i
__device__ __forceinline__ void dwt_pair_edge(const float* __restrict__ src, int L, int k,
                                              float& a, float& b) {
    const float LO[8] = {DL0,DL1,DL2,DL3,DL4,DL5,DL6,DL7};
    const float HI[8] = {DH0,DH1,DH2,DH3,DH4,DH5,DH6,DH7};
    a = 0.f; b = 0.f;
    int base = 2*k - 6;
#pragma unroll
    for (int t = 0; t < 8; ++t) {
        int j = base + t;
        int i = (j < 0) ? -j : j;
        if (i >= L) i = 2*L - 2 - i;
        float v = src[i];
        a += v * LO[7-t];
        b += v * HI[7-t];
    }
}

// Interior fast path: valid when base >= 0 and base+7 <= L-1  (k>=3 && 2k+1<L)
__device__ __forceinline__ void dwt_pair_int(const float* __restrict__ src, int k,
                                             float& a, float& b) {
    int base = 2*k - 6;
    float v0 = src[base],     v1 = src[base + 1], v2 = src[base + 2], v3 = src[base + 3];
    float v4 = src[base + 4], v5 = src[base + 5], v6 = src[base + 6], v7 = src[base + 7];
    a = v0*DL7 + v1*DL6 + v2*DL5 + v3*DL4 + v4*DL3 + v5*DL2 + v6*DL1 + v7*DL0;
    b = v0*DH7 + v1*DH6 + v2*DH5 + v3*DH4 + v4*DH3 + v5*DH2 + v6*DH1 + v7*DH0;
}

// Pair-form lowpass-only inverse: outputs o=2m (even) and o=2m+1 (odd) share ca[m..m+3].
// No bounds checks needed: for all our (O,C), (O-1)/2 + 3 < C holds.
__device__ __forceinline__ void idwt_lo_pair(const float* __restrict__ ca, int m,
                                             float& ev, float& od) {
    float c0 = ca[m], c1 = ca[m+1], c2 = ca[m+2], c3 = ca[m+3];
    ev = c0*DL1 + c1*DL3 + c2*DL5 + c3*DL7;
    od = c0*DL0 + c1*DL2 + c2*DL4 + c3*DL6;
}

// ---------------- Kernel A: baseline removal + forward 4-level DWT ----------------
// LDS 40.3 KB -> 4 blocks/CU. Forward-DWT loops process TWO adjacent outputs per
// thread-iteration: k and k+1 share 6 of 8 taps -> 10 LDS loads + 32 FMA per pair
// (vs 16+32) and half the loop/address overhead. Edge outputs use the slow path.
// Block 0 additionally zero-inits the median bins/state (replaces kinit launch;
// stream ordering makes it visible to the khist launched after kernelA).
__global__ __launch_bounds__(NT, 4) void kernelA(const float* __restrict__ x,
                                                 float* __restrict__ g_d1, float* __restrict__ g_d2,
                                                 float* __restrict__ g_d3, float* __restrict__ g_d4,
                                                 float* __restrict__ g_ca4,
                                                 unsigned* __restrict__ bins,
                                                 unsigned* __restrict__ state) {
    __shared__ float sig0[5000];
    __shared__ float pyr[5028];    // levels 1..8: 2503,1255,631,319,163,85,46,26
    __shared__ float redm[9][4];
    __shared__ int depth_s;

    const int row = blockIdx.x;
    const int tid = threadIdx.x;

    if (row == 0) {
        for (int i = tid; i < 2048; i += NT) bins[i] = 0u;
        if (tid == 0) { state[0] = 0u; state[1] = 979967u; }  // k = (1959936-1)//2
    }

    {
        const float4* xr4 = (const float4*)(x + (size_t)row * LSIG);
        float4* s4 = (float4*)sig0;
        for (int i = tid; i < 1250; i += NT) s4[i] = xr4[i];
    }
    __syncthreads();

    const int lensA[10] = {5000, 2503, 1255, 631, 319, 163, 85, 46, 26, 16};
    const int offs[8]   = {0, 2503, 3758, 4389, 4708, 4871, 4956, 5002};

    // ---- phase 1: pyramid; per-thread SSD accumulators (t=8 lowpass is discarded) ----
    float sp[9];
    const float* src = sig0;
#pragma unroll
    for (int t = 0; t < 9; ++t) {
        const int L   = lensA[t];
        const int Lo  = lensA[t + 1];
        const int kHi = (L - 2) >> 1;           // max k with 2k+1 <= L-1
        float* lp = pyr + ((t < 8) ? offs[t] : 0);
        float part = 0.f;
        const int Pc = (Lo + 1) >> 1;           // output pairs (last may be single)
        for (int pp = tid; pp < Pc; pp += NT) {
            const int k0 = 2 * pp;
            const int k1 = k0 + 1;
            if (k1 < Lo) {
                float a0, b0, a1, b1;
                if (pp >= 2 && k1 <= kHi) {      // both outputs interior
                    const int base = 4 * pp - 6; // >= 2; base+9 = 2*k1+1 <= L-1
                    float v0=src[base],  v1=src[base+1],v2=src[base+2],v3=src[base+3],v4=src[base+4];
                    float v5=src[base+5],v6=src[base+6],v7=src[base+7],v8=src[base+8],v9=src[base+9];
                    a0 = v0*DL7+v1*DL6+v2*DL5+v3*DL4+v4*DL3+v5*DL2+v6*DL1+v7*DL0;
                    b0 = v0*DH7+v1*DH6+v2*DH5+v3*DH4+v4*DH3+v5*DH2+v6*DH1+v7*DH0;
                    a1 = v2*DL7+v3*DL6+v4*DL5+v5*DL4+v6*DL3+v7*DL2+v8*DL1+v9*DL0;
                    b1 = v2*DH7+v3*DH6+v4*DH5+v5*DH4+v6*DH3+v7*DH2+v8*DH1+v9*DH0;
                } else {
                    if (k0 >= 3 && k0 <= kHi) dwt_pair_int(src, k0, a0, b0);
                    else                      dwt_pair_edge(src, L, k0, a0, b0);
                    if (k1 >= 3 && k1 <= kHi) dwt_pair_int(src, k1, a1, b1);
                    else                      dwt_pair_edge(src, L, k1, a1, b1);
                }
                if (t < 8) { lp[k0] = a0; lp[k1] = a1; }
                part += b0 * b0 + b1 * b1;
            } else {                             // odd Lo leftover: single output k0
                float a0, b0;
                if (k0 >= 3 && k0 <= kHi) dwt_pair_int(src, k0, a0, b0);
                else                      dwt_pair_edge(src, L, k0, a0, b0);
                if (t < 8) lp[k0] = a0;
                part += b0 * b0;
            }
        }
        sp[t] = part;
        __syncthreads();
        src = lp;
    }

    // ---- one reduction for all 9 SSDs, then depth decision ----
#pragma unroll
    for (int t = 0; t < 9; ++t) {
        float p = sp[t];
#pragma unroll
        for (int o = 32; o; o >>= 1) p += __shfl_down(p, o, 64);
        if ((tid & 63) == 0) redm[t][tid >> 6] = p;
    }
    __syncthreads();
    if (tid == 0) {
        float ssds[9];
#pragma unroll
        for (int t = 0; t < 9; ++t) ssds[t] = redm[t][0] + redm[t][1] + redm[t][2] + redm[t][3];
        int dd = -1;
        for (int t = 2; t <= 8; ++t)
            if (dd < 0 && ssds[t - 2] > ssds[t - 1] && ssds[t - 1] < ssds[t]) dd = t;
        depth_s = (dd < 0) ? 8 : dd;
    }
    __syncthreads();
    const int d = depth_s;   // in [2,8]; sigs[d] = pyr + offs[d-1]

    // ---- baseline recon: (idwt_lo)^d of sigs[d], ping-pong in dead prefix; subtract ----
    const float* cur = pyr + offs[d - 1];
    for (int k = d - 1; k >= 1; --k) {
        const int ol = lensA[k];
        float* dst = (k & 1) ? pyr : (pyr + 2503);   // slot0 / slot1
        const int np = (ol + 1) >> 1;
        for (int m = tid; m < np; m += NT) {
            float ev, od;
            idwt_lo_pair(cur, m, ev, od);
            dst[2*m] = ev;
            if (2*m + 1 < ol) dst[2*m + 1] = od;
        }
        __syncthreads();
        cur = dst;
    }
    // final upsample (len 2503 -> 5000) fused with subtract; 2 pairs per iteration:
    // m, m+1 share c1..c3 -> 5 loads for 4 outputs. 2500 pairs -> 1250 iterations.
    for (int q = tid; q < 1250; q += NT) {
        const int m = 2 * q;
        float c0 = cur[m], c1 = cur[m+1], c2 = cur[m+2], c3 = cur[m+3], c4 = cur[m+4];
        float ev0 = c0*DL1 + c1*DL3 + c2*DL5 + c3*DL7;
        float od0 = c0*DL0 + c1*DL2 + c2*DL4 + c3*DL6;
        float ev1 = c1*DL1 + c2*DL3 + c3*DL5 + c4*DL7;
        float od1 = c1*DL0 + c2*DL2 + c3*DL4 + c4*DL6;
        sig0[2*m]     -= ev0;
        sig0[2*m + 1] -= od0;
        sig0[2*m + 2] -= ev1;
        sig0[2*m + 3] -= od1;
    }
    __syncthreads();

    // ---- phase 2: 4-level forward DWT of residual; details -> global, lp in pyr ----
    const int l2[5] = {5000, 2503, 1255, 631, 319};
    src = sig0;
#pragma unroll
    for (int lev = 0; lev < 4; ++lev) {
        const int L   = l2[lev];
        const int Lo  = l2[lev + 1];
        const int kHi = (L - 2) >> 1;
        float* lp = pyr + ((lev & 1) ? 2503 : 0);
        float* hg;
        if      (lev == 0) hg = g_d1 + (size_t)row * 2503;
        else if (lev == 1) hg = g_d2 + (size_t)row * 1255;
        else if (lev == 2) hg = g_d3 + (size_t)row * 631;
        else               hg = g_d4 + (size_t)row * 319;
        const int Pc = (Lo + 1) >> 1;
        for (int pp = tid; pp < Pc; pp += NT) {
            const int k0 = 2 * pp;
            const int k1 = k0 + 1;
            if (k1 < Lo) {
                float a0, b0, a1, b1;
                if (pp >= 2 && k1 <= kHi) {
                    const int base = 4 * pp - 6;
                    float v0=src[base],  v1=src[base+1],v2=src[base+2],v3=src[base+3],v4=src[base+4];
                    float v5=src[base+5],v6=src[base+6],v7=src[base+7],v8=src[base+8],v9=src[base+9];
                    a0 = v0*DL7+v1*DL6+v2*DL5+v3*DL4+v4*DL3+v5*DL2+v6*DL1+v7*DL0;
                    b0 = v0*DH7+v1*DH6+v2*DH5+v3*DH4+v4*DH3+v5*DH2+v6*DH1+v7*DH0;
                    a1 = v2*DL7+v3*DL6+v4*DL5+v5*DL4+v6*DL3+v7*DL2+v8*DL1+v9*DL0;
                    b1 = v2*DH7+v3*DH6+v4*DH5+v5*DH4+v6*DH3+v7*DH2+v8*DH1+v9*DH0;
                } else {
                    if (k0 >= 3 && k0 <= kHi) dwt_pair_int(src, k0, a0, b0);
                    else                      dwt_pair_edge(src, L, k0, a0, b0);
                    if (k1 >= 3 && k1 <= kHi) dwt_pair_int(src, k1, a1, b1);
                    else                      dwt_pair_edge(src, L, k1, a1, b1);
                }
                lp[k0] = a0; lp[k1] = a1;
                hg[k0] = b0; hg[k1] = b1;
            } else {
                float a0, b0;
                if (k0 >= 3 && k0 <= kHi) dwt_pair_int(src, k0, a0, b0);
                else                      dwt_pair_edge(src, L, k0, a0, b0);
                lp[k0] = a0;
                hg[k0] = b0;
            }
        }
        __syncthreads();
        src = lp;
    }
    float* cg = g_ca4 + (size_t)row * 319;
    for (int i = tid; i < 319; i += NT) cg[i] = pyr[2503 + i];
}

// ---------------- median radix-select kernels ----------------
__global__ void khist(const float* __restrict__ data, int n, unsigned* __restrict__ bins,
                      const unsigned* __restrict__ state, int shift, unsigned binmask,
                      unsigned prefmask) {
    __shared__ unsigned h[2048];
    const int nb = (int)binmask + 1;
    for (int i = threadIdx.x; i < nb; i += blockDim.x) h[i] = 0u;
    __syncthreads();
    const unsigned pref = state[0] & prefmask;
    const int stride = gridDim.x * blockDim.x;
    for (int i = blockIdx.x * blockDim.x + threadIdx.x; i < n; i += stride) {
        unsigned key = __float_as_uint(fabsf(data[i]));
        if ((key & prefmask) == pref) atomicAdd(&h[(key >> shift) & binmask], 1u);
    }
    __syncthreads();
    for (int i = threadIdx.x; i < nb; i += blockDim.x)
        if (h[i]) atomicAdd(&bins[i], h[i]);
}

// Radix-select step, LDS-accelerated (proven in R4: ~26 µs/launch -> ~4 µs).
// All 256 threads copy bins -> LDS and build chunk sums (parallel, before the
// barrier); thread 0 walks chunk sums + crossing chunk in LDS, reproducing the
// original cum/break semantics exactly (incl. the b = nbins-1 fall-through).
__global__ void kselect(unsigned* bins, unsigned* state,
                        float* sigma_out, int shift, int nbins, int final_pass) {
    __shared__ unsigned sb[2048];
    __shared__ unsigned cs[256];
    const int tid = threadIdx.x;
    const int CH  = nbins >> 8;              // bins per chunk: 8 (2048) or 4 (1024)
    unsigned sum = 0;
    for (int j = 0; j < CH; ++j) {
        unsigned v = bins[tid * CH + j];
        sb[tid * CH + j] = v;
        sum += v;
    }
    cs[tid] = sum;
    __syncthreads();
    if (tid == 0) {
        const unsigned krem = state[1];
        unsigned cum = 0;
        int ch = 0;
        for (; ch < 256; ++ch) {
            unsigned c = cs[ch];
            if (cum + c > krem) break;
            cum += c;
        }
        int b;
        if (ch == 256) {
            // no crossing: original loop falls through with b = nbins-1 and
            // cum = sum of bins[0..nbins-2]
            b = nbins - 1;
            cum -= sb[nbins - 1];
        } else {
            b = ch * CH;
            for (; b < nbins - 1; ++b) {
                unsigned c = sb[b];
                if (cum + c > krem) break;
                cum += c;
            }
        }
        unsigned prefix = state[0] | ((unsigned)b << shift);
        state[0] = prefix;
        state[1] = krem - cum;
        if (final_pass) *sigma_out = __uint_as_float(prefix) / 0.6745f;
    }
    __syncthreads();
    for (int i = tid; i < nbins; i += 256) bins[i] = 0u;
}

// ---------------- Kernel C: threshold + inverse DWT + normalize ----------------
// idwt loop processes TWO pairs (4 outputs) per thread-iteration: pairs m, m+1
// share 3 of 4 ca/cd taps -> 10 LDS loads per 4 outputs (vs 16). O % 4 == 0 at
// every level and max read index is exactly C-1 (319/631/1255/2503 verified).
__global__ __launch_bounds__(NT, 4) void kernelC(const float* __restrict__ g_d1,
                                                 const float* __restrict__ g_d2,
                                                 const float* __restrict__ g_d3,
                                                 const float* __restrict__ g_d4,
                                                 const float* __restrict__ g_ca4,
                                                 const float* __restrict__ sigma_p,
                                                 float* __restrict__ out) {
    __shared__ float A[5000];
    __shared__ float B[2504];
    __shared__ float Dd[2503];
    __shared__ double redd[4][2];
    __shared__ float sg;

    const int row = blockIdx.x;
    const int tid = threadIdx.x;
    if (tid == 0) sg = *sigma_p;
    for (int i = tid; i < 319; i += NT) A[i] = g_ca4[(size_t)row * 319 + i];
    __syncthreads();
    const float sigma = sg;

    const int Cs[4] = {319, 631, 1255, 2503};
    const int Os[4] = {632, 1256, 2504, 5000};

#pragma unroll
    for (int s = 0; s < 4; ++s) {
        const int C = Cs[s];
        const int O = Os[s];
        const float* dg;
        if      (s == 0) dg = g_d4 + (size_t)row * 319;
        else if (s == 1) dg = g_d3 + (size_t)row * 631;
        else if (s == 2) dg = g_d2 + (size_t)row * 1255;
        else             dg = g_d1 + (size_t)row * 2503;
        const float* spb = (s & 1) ? B : A;   // 0:A 1:B 2:A 3:B
        float* dp        = (s & 1) ? A : B;
        for (int i = tid; i < C; i += NT) {
            float v = dg[i];
            Dd[i] = (v < sigma) ? 0.f : v;   // raw-value threshold, per reference
        }
        __syncthreads();
        const int nq = O >> 2;               // pair-pairs; O % 4 == 0 for all levels
        for (int q = tid; q < nq; q += NT) {
            const int m = 2 * q;
            float c0 = spb[m], c1 = spb[m+1], c2 = spb[m+2], c3 = spb[m+3], c4 = spb[m+4];
            float e0 = Dd[m],  e1 = Dd[m+1],  e2 = Dd[m+2],  e3 = Dd[m+3],  e4 = Dd[m+4];
            float ev0 = c0*DL1 + c1*DL3 + c2*DL5 + c3*DL7 + e0*DH1 + e1*DH3 + e2*DH5 + e3*DH7;
            float od0 = c0*DL0 + c1*DL2 + c2*DL4 + c3*DL6 + e0*DH0 + e1*DH2 + e2*DH4 + e3*DH6;
            float ev1 = c1*DL1 + c2*DL3 + c3*DL5 + c4*DL7 + e1*DH1 + e2*DH3 + e3*DH5 + e4*DH7;
            float od1 = c1*DL0 + c2*DL2 + c3*DL4 + c4*DL6 + e1*DH0 + e2*DH2 + e3*DH4 + e4*DH6;
            dp[2*m]     = ev0;
            dp[2*m + 1] = od0;
            dp[2*m + 2] = ev1;
            dp[2*m + 3] = od1;
        }
        __syncthreads();
    }

    // normalize A[0..4999]: single-pass sum/sumsq in double, std(ddof=1), nan_to_num
    double s1 = 0.0, s2 = 0.0;
    for (int i = tid; i < 5000; i += NT) {
        double v = (double)A[i];
        s1 += v;
        s2 += v * v;
    }
#pragma unroll
    for (int o = 32; o; o >>= 1) {
        s1 += __shfl_down(s1, o, 64);
        s2 += __shfl_down(s2, o, 64);
    }
    if ((tid & 63) == 0) { redd[tid >> 6][0] = s1; redd[tid >> 6][1] = s2; }
    __syncthreads();
    double sum  = redd[0][0] + redd[1][0] + redd[2][0] + redd[3][0];
    double sumq = redd[0][1] + redd[1][1] + redd[2][1] + redd[3][1];
    double mean = sum / 5000.0;
    double var  = (sumq - sum * mean) / 4999.0;

    float meanf = (float)mean;
    float inv = 1.0f / (float)sqrt(var);
    float* orow = out + (size_t)row * 5000;
    for (int i = tid; i < 5000; i += NT) {
        float r = (A[i] - meanf) * inv;
        if (isnan(r)) r = 0.f;
        else if (isinf(r)) r = copysignf(3.4028234663852886e38f, r);
        orow[i] = r;
    }
}

extern "C" void kernel_launch(void* const* d_in, const int* in_sizes, int n_in,
                              void* d_out, int out_size, void* d_ws, size_t ws_size,
                              hipStream_t stream) {
    const float* x = (const float*)d_in[0];
    float* out = (float*)d_out;

    const size_t n1 = (size_t)NROWS * 2503;
    const size_t n2 = (size_t)NROWS * 1255;
    const size_t n3 = (size_t)NROWS * 631;
    const size_t n4 = (size_t)NROWS * 319;

    float* w    = (float*)d_ws;
    float* d1   = w;
    float* d2   = d1 + n1;
    float* d3   = d2 + n2;
    float* d4   = d3 + n3;
    float* ca4  = d4 + n4;
    unsigned* bins  = (unsigned*)(ca4 + n4);
    unsigned* state = bins + 2048;
    float* sigp = (float*)(state + 2);
    const int n = (int)n4;  // 1,959,936

    hipLaunchKernelGGL(kernelA, dim3(NROWS), dim3(NT), 0, stream, x, d1, d2, d3, d4, ca4, bins, state);
    hipLaunchKernelGGL(khist, dim3(512), dim3(256), 0, stream, d4, n, bins, state, 21, 2047u, 0x00000000u);
    hipLaunchKernelGGL(kselect, dim3(1), dim3(256), 0, stream, bins, state, sigp, 21, 2048, 0);
    hipLaunchKernelGGL(khist, dim3(512), dim3(256), 0, stream, d4, n, bins, state, 10, 2047u, 0xFFE00000u);
    hipLaunchKernelGGL(kselect, dim3(1), dim3(256), 0, stream, bins, state, sigp, 10, 2048, 0);
    hipLaunchKernelGGL(khist, dim3(512), dim3(256), 0, stream, d4, n, bins, state, 0, 1023u, 0xFFFFFC00u);
    hipLaunchKernelGGL(kselect, dim3(1), dim3(256), 0, stream, bins, state, sigp, 0, 1024, 1);
    hipLaunchKernelGGL(kernelC, dim3(NROWS), dim3(NT), 0, stream, d1, d2, d3, d4, ca4, sigp, out);
}

// Round 7
// 416.308 us; speedup vs baseline: 1.0856x; 1.0856x over previous
//
#include <hip/hip_runtime.h>
#include <math.h>

#define NROWS 6144
#define LSIG  5000
#define NT    256

// db4 decomposition filters (natural order), hi[k] = (-1)^(k+1) lo[k]
#define DL0 (-0.010597401784997278f)
#define DL1 ( 0.032883011666982945f)
#define DL2 ( 0.030841381835986965f)
#define DL3 (-0.18703481171888114f)
#define DL4 (-0.02798376941698385f)
#define DL5 ( 0.6308807679295904f)
#define DL6 ( 0.7148465705525415f)
#define DL7 ( 0.23037781330885523f)
#define DH0 ( 0.010597401784997278f)
#define DH1 ( 0.032883011666982945f)
#define DH2 (-0.030841381835986965f)
#define DH3 (-0.18703481171888114f)
#define DH4 ( 0.02798376941698385f)
#define DH5 ( 0.6308807679295904f)
#define DH6 (-0.7148465705525415f)
#define DH7 ( 0.23037781330885523f)

// Forward DWT (edge path): ca[k] = sum_t xp[2k+t]*lo[7-t].
// xp index map (reflect pad 7,7 drop first): j=2k+t-6; i=|j|; if i>=L -> 2L-2-i
__device__ __forceinline__ void dwt_pair_edge(const float* __restrict__ src, int L, int k,
                                              float& a, float& b) {
    const float LO[8] = {DL0,DL1,DL2,DL3,DL4,DL5,DL6,DL7};
    const float HI[8] = {DH0,DH1,DH2,DH3,DH4,DH5,DH6,DH7};
    a = 0.f; b = 0.f;
    int base = 2*k - 6;
#pragma unroll
    for (int t = 0; t < 8; ++t) {
        int j = base + t;
        int i = (j < 0) ? -j : j;
        if (i >= L) i = 2*L - 2 - i;
        float v = src[i];
        a += v * LO[7-t];
        b += v * HI[7-t];
    }
}

// Interior fast path: valid when base >= 0 and base+7 <= L-1  (k>=3 && 2k+1<L)
// Lanes at stride-1 k -> LDS addresses at stride 2 floats -> 2-way bank
// aliasing, which is FREE on gfx950 (m136). Do NOT pair adjacent outputs per
// lane: that makes stride 4 floats -> 8-way conflict (measured R6: 18.6M
// conflict cycles, kernelA 152 -> 193 µs regression).
__device__ __forceinline__ void dwt_pair_int(const float* __restrict__ src, int k,
                                             float& a, float& b) {
    int base = 2*k - 6;
    float v0 = src[base],     v1 = src[base + 1], v2 = src[base + 2], v3 = src[base + 3];
    float v4 = src[base + 4], v5 = src[base + 5], v6 = src[base + 6], v7 = src[base + 7];
    a = v0*DL7 + v1*DL6 + v2*DL5 + v3*DL4 + v4*DL3 + v5*DL2 + v6*DL1 + v7*DL0;
    b = v0*DH7 + v1*DH6 + v2*DH5 + v3*DH4 + v4*DH3 + v5*DH2 + v6*DH1 + v7*DH0;
}

// Pair-form lowpass-only inverse: outputs o=2m (even) and o=2m+1 (odd) share ca[m..m+3].
// No bounds checks needed: for all our (O,C), (O-1)/2 + 3 < C holds.
__device__ __forceinline__ void idwt_lo_pair(const float* __restrict__ ca, int m,
                                             float& ev, float& od) {
    float c0 = ca[m], c1 = ca[m+1], c2 = ca[m+2], c3 = ca[m+3];
    ev = c0*DL1 + c1*DL3 + c2*DL5 + c3*DL7;
    od = c0*DL0 + c1*DL2 + c2*DL4 + c3*DL6;
}

// ---------------- Kernel A: baseline removal + forward 4-level DWT ----------------
// LDS 40.3 KB -> 4 blocks/CU. Forward loops are per-output (stride-2 LDS, free
// 2-way aliasing — see dwt_pair_int note). Block 0 zero-inits median bins/state
// (replaces kinit launch; stream ordering makes it visible to khist).
__global__ __launch_bounds__(NT, 4) void kernelA(const float* __restrict__ x,
                                                 float* __restrict__ g_d1, float* __restrict__ g_d2,
                                                 float* __restrict__ g_d3, float* __restrict__ g_d4,
                                                 float* __restrict__ g_ca4,
                                                 unsigned* __restrict__ bins,
                                                 unsigned* __restrict__ state) {
    __shared__ float sig0[5000];
    __shared__ float pyr[5028];    // levels 1..8: 2503,1255,631,319,163,85,46,26
    __shared__ float redm[9][4];
    __shared__ int depth_s;

    const int row = blockIdx.x;
    const int tid = threadIdx.x;

    if (row == 0) {
        for (int i = tid; i < 2048; i += NT) bins[i] = 0u;
        if (tid == 0) { state[0] = 0u; state[1] = 979967u; }  // k = (1959936-1)//2
    }

    {
        const float4* xr4 = (const float4*)(x + (size_t)row * LSIG);
        float4* s4 = (float4*)sig0;
        for (int i = tid; i < 1250; i += NT) s4[i] = xr4[i];
    }
    __syncthreads();

    const int lensA[10] = {5000, 2503, 1255, 631, 319, 163, 85, 46, 26, 16};
    const int offs[8]   = {0, 2503, 3758, 4389, 4708, 4871, 4956, 5002};

    // ---- phase 1: pyramid; per-thread SSD accumulators (t=8 lowpass is discarded) ----
    float sp[9];
    const float* src = sig0;
#pragma unroll
    for (int t = 0; t < 9; ++t) {
        const int L   = lensA[t];
        const int Lo  = lensA[t + 1];
        const int kHi = (L - 2) >> 1;           // max k with 2k+1 <= L-1
        float* lp = pyr + ((t < 8) ? offs[t] : 0);
        float part = 0.f;
        for (int k = tid; k < Lo; k += NT) {
            float a, b;
            if (k >= 3 && k <= kHi) dwt_pair_int(src, k, a, b);
            else                    dwt_pair_edge(src, L, k, a, b);
            if (t < 8) lp[k] = a;
            part += b * b;
        }
        sp[t] = part;
        __syncthreads();
        src = lp;
    }

    // ---- one reduction for all 9 SSDs, then depth decision ----
#pragma unroll
    for (int t = 0; t < 9; ++t) {
        float p = sp[t];
#pragma unroll
        for (int o = 32; o; o >>= 1) p += __shfl_down(p, o, 64);
        if ((tid & 63) == 0) redm[t][tid >> 6] = p;
    }
    __syncthreads();
    if (tid == 0) {
        float ssds[9];
#pragma unroll
        for (int t = 0; t < 9; ++t) ssds[t] = redm[t][0] + redm[t][1] + redm[t][2] + redm[t][3];
        int dd = -1;
        for (int t = 2; t <= 8; ++t)
            if (dd < 0 && ssds[t - 2] > ssds[t - 1] && ssds[t - 1] < ssds[t]) dd = t;
        depth_s = (dd < 0) ? 8 : dd;
    }
    __syncthreads();
    const int d = depth_s;   // in [2,8]; sigs[d] = pyr + offs[d-1]

    // ---- baseline recon: (idwt_lo)^d of sigs[d], ping-pong in dead prefix; subtract ----
    const float* cur = pyr + offs[d - 1];
    for (int k = d - 1; k >= 1; --k) {
        const int ol = lensA[k];
        float* dst = (k & 1) ? pyr : (pyr + 2503);   // slot0 / slot1
        const int np = (ol + 1) >> 1;
        for (int m = tid; m < np; m += NT) {
            float ev, od;
            idwt_lo_pair(cur, m, ev, od);
            dst[2*m] = ev;
            if (2*m + 1 < ol) dst[2*m + 1] = od;
        }
        __syncthreads();
        cur = dst;
    }
    // final upsample (len 2503 -> 5000) fused with subtract; 2 pairs per iteration:
    // m, m+1 share c1..c3 -> 5 loads for 4 outputs; lane stride 2 floats = free.
    for (int q = tid; q < 1250; q += NT) {
        const int m = 2 * q;
        float c0 = cur[m], c1 = cur[m+1], c2 = cur[m+2], c3 = cur[m+3], c4 = cur[m+4];
        float ev0 = c0*DL1 + c1*DL3 + c2*DL5 + c3*DL7;
        float od0 = c0*DL0 + c1*DL2 + c2*DL4 + c3*DL6;
        float ev1 = c1*DL1 + c2*DL3 + c3*DL5 + c4*DL7;
        float od1 = c1*DL0 + c2*DL2 + c3*DL4 + c4*DL6;
        sig0[2*m]     -= ev0;
        sig0[2*m + 1] -= od0;
        sig0[2*m + 2] -= ev1;
        sig0[2*m + 3] -= od1;
    }
    __syncthreads();

    // ---- phase 2: 4-level forward DWT of residual; details -> global, lp in pyr ----
    const int l2[5] = {5000, 2503, 1255, 631, 319};
    src = sig0;
#pragma unroll
    for (int lev = 0; lev < 4; ++lev) {
        const int L   = l2[lev];
        const int Lo  = l2[lev + 1];
        const int kHi = (L - 2) >> 1;
        float* lp = pyr + ((lev & 1) ? 2503 : 0);
        float* hg;
        if      (lev == 0) hg = g_d1 + (size_t)row * 2503;
        else if (lev == 1) hg = g_d2 + (size_t)row * 1255;
        else if (lev == 2) hg = g_d3 + (size_t)row * 631;
        else               hg = g_d4 + (size_t)row * 319;
        for (int k = tid; k < Lo; k += NT) {
            float a, b;
            if (k >= 3 && k <= kHi) dwt_pair_int(src, k, a, b);
            else                    dwt_pair_edge(src, L, k, a, b);
            lp[k] = a;
            hg[k] = b;
        }
        __syncthreads();
        src = lp;
    }
    float* cg = g_ca4 + (size_t)row * 319;
    for (int i = tid; i < 319; i += NT) cg[i] = pyr[2503 + i];
}

// ---------------- median radix-select kernels ----------------
__global__ void khist(const float* __restrict__ data, int n, unsigned* __restrict__ bins,
                      const unsigned* __restrict__ state, int shift, unsigned binmask,
                      unsigned prefmask) {
    __shared__ unsigned h[2048];
    const int nb = (int)binmask + 1;
    for (int i = threadIdx.x; i < nb; i += blockDim.x) h[i] = 0u;
    __syncthreads();
    const unsigned pref = state[0] & prefmask;
    const int stride = gridDim.x * blockDim.x;
    for (int i = blockIdx.x * blockDim.x + threadIdx.x; i < n; i += stride) {
        unsigned key = __float_as_uint(fabsf(data[i]));
        if ((key & prefmask) == pref) atomicAdd(&h[(key >> shift) & binmask], 1u);
    }
    __syncthreads();
    for (int i = threadIdx.x; i < nb; i += blockDim.x)
        if (h[i]) atomicAdd(&bins[i], h[i]);
}

// Radix-select step, LDS-accelerated (proven in R4: ~26 µs/launch -> ~4 µs).
// All 256 threads copy bins -> LDS and build chunk sums (parallel, before the
// barrier); thread 0 walks chunk sums + crossing chunk in LDS, reproducing the
// original cum/break semantics exactly (incl. the b = nbins-1 fall-through).
__global__ void kselect(unsigned* bins, unsigned* state,
                        float* sigma_out, int shift, int nbins, int final_pass) {
    __shared__ unsigned sb[2048];
    __shared__ unsigned cs[256];
    const int tid = threadIdx.x;
    const int CH  = nbins >> 8;              // bins per chunk: 8 (2048) or 4 (1024)
    unsigned sum = 0;
    for (int j = 0; j < CH; ++j) {
        unsigned v = bins[tid * CH + j];
        sb[tid * CH + j] = v;
        sum += v;
    }
    cs[tid] = sum;
    __syncthreads();
    if (tid == 0) {
        const unsigned krem = state[1];
        unsigned cum = 0;
        int ch = 0;
        for (; ch < 256; ++ch) {
            unsigned c = cs[ch];
            if (cum + c > krem) break;
            cum += c;
        }
        int b;
        if (ch == 256) {
            // no crossing: original loop falls through with b = nbins-1 and
            // cum = sum of bins[0..nbins-2]
            b = nbins - 1;
            cum -= sb[nbins - 1];
        } else {
            b = ch * CH;
            for (; b < nbins - 1; ++b) {
                unsigned c = sb[b];
                if (cum + c > krem) break;
                cum += c;
            }
        }
        unsigned prefix = state[0] | ((unsigned)b << shift);
        state[0] = prefix;
        state[1] = krem - cum;
        if (final_pass) *sigma_out = __uint_as_float(prefix) / 0.6745f;
    }
    __syncthreads();
    for (int i = tid; i < nbins; i += 256) bins[i] = 0u;
}

// ---------------- Kernel C: threshold + inverse DWT + normalize ----------------
// idwt loop processes TWO pairs (4 outputs) per thread-iteration: pairs m, m+1
// share 3 of 4 ca/cd taps -> 10 LDS loads per 4 outputs (vs 16). Lane stride is
// 2 floats (m = 2*tid) -> free 2-way aliasing, no conflicts (unlike stride-4).
// O % 4 == 0 at every level; max read index is exactly C-1 (319/631/1255/2503).
__global__ __launch_bounds__(NT, 4) void kernelC(const float* __restrict__ g_d1,
                                                 const float* __restrict__ g_d2,
                                                 const float* __restrict__ g_d3,
                                                 const float* __restrict__ g_d4,
                                                 const float* __restrict__ g_ca4,
                                                 const float* __restrict__ sigma_p,
                                                 float* __restrict__ out) {
    __shared__ float A[5000];
    __shared__ float B[2504];
    __shared__ float Dd[2503];
    __shared__ double redd[4][2];
    __shared__ float sg;

    const int row = blockIdx.x;
    const int tid = threadIdx.x;
    if (tid == 0) sg = *sigma_p;
    for (int i = tid; i < 319; i += NT) A[i] = g_ca4[(size_t)row * 319 + i];
    __syncthreads();
    const float sigma = sg;

    const int Cs[4] = {319, 631, 1255, 2503};
    const int Os[4] = {632, 1256, 2504, 5000};

#pragma unroll
    for (int s = 0; s < 4; ++s) {
        const int C = Cs[s];
        const int O = Os[s];
        const float* dg;
        if      (s == 0) dg = g_d4 + (size_t)row * 319;
        else if (s == 1) dg = g_d3 + (size_t)row * 631;
        else if (s == 2) dg = g_d2 + (size_t)row * 1255;
        else             dg = g_d1 + (size_t)row * 2503;
        const float* spb = (s & 1) ? B : A;   // 0:A 1:B 2:A 3:B
        float* dp        = (s & 1) ? A : B;
        for (int i = tid; i < C; i += NT) {
            float v = dg[i];
            Dd[i] = (v < sigma) ? 0.f : v;   // raw-value threshold, per reference
        }
        __syncthreads();
        const int nq = O >> 2;               // pair-pairs; O % 4 == 0 for all levels
        for (int q = tid; q < nq; q += NT) {
            const int m = 2 * q;
            float c0 = spb[m], c1 = spb[m+1], c2 = spb[m+2], c3 = spb[m+3], c4 = spb[m+4];
            float e0 = Dd[m],  e1 = Dd[m+1],  e2 = Dd[m+2],  e3 = Dd[m+3],  e4 = Dd[m+4];
            float ev0 = c0*DL1 + c1*DL3 + c2*DL5 + c3*DL7 + e0*DH1 + e1*DH3 + e2*DH5 + e3*DH7;
            float od0 = c0*DL0 + c1*DL2 + c2*DL4 + c3*DL6 + e0*DH0 + e1*DH2 + e2*DH4 + e3*DH6;
            float ev1 = c1*DL1 + c2*DL3 + c3*DL5 + c4*DL7 + e1*DH1 + e2*DH3 + e3*DH5 + e4*DH7;
            float od1 = c1*DL0 + c2*DL2 + c3*DL4 + c4*DL6 + e1*DH0 + e2*DH2 + e3*DH4 + e4*DH6;
            dp[2*m]     = ev0;
            dp[2*m + 1] = od0;
            dp[2*m + 2] = ev1;
            dp[2*m + 3] = od1;
        }
        __syncthreads();
    }

    // normalize A[0..4999]: single-pass sum/sumsq in double, std(ddof=1), nan_to_num
    double s1 = 0.0, s2 = 0.0;
    for (int i = tid; i < 5000; i += NT) {
        double v = (double)A[i];
        s1 += v;
        s2 += v * v;
    }
#pragma unroll
    for (int o = 32; o; o >>= 1) {
        s1 += __shfl_down(s1, o, 64);
        s2 += __shfl_down(s2, o, 64);
    }
    if ((tid & 63) == 0) { redd[tid >> 6][0] = s1; redd[tid >> 6][1] = s2; }
    __syncthreads();
    double sum  = redd[0][0] + redd[1][0] + redd[2][0] + redd[3][0];
    double sumq = redd[0][1] + redd[1][1] + redd[2][1] + redd[3][1];
    double mean = sum / 5000.0;
    double var  = (sumq - sum * mean) / 4999.0;

    float meanf = (float)mean;
    float inv = 1.0f / (float)sqrt(var);
    float* orow = out + (size_t)row * 5000;
    for (int i = tid; i < 5000; i += NT) {
        float r = (A[i] - meanf) * inv;
        if (isnan(r)) r = 0.f;
        else if (isinf(r)) r = copysignf(3.4028234663852886e38f, r);
        orow[i] = r;
    }
}

extern "C" void kernel_launch(void* const* d_in, const int* in_sizes, int n_in,
                              void* d_out, int out_size, void* d_ws, size_t ws_size,
                              hipStream_t stream) {
    const float* x = (const float*)d_in[0];
    float* out = (float*)d_out;

    const size_t n1 = (size_t)NROWS * 2503;
    const size_t n2 = (size_t)NROWS * 1255;
    const size_t n3 = (size_t)NROWS * 631;
    const size_t n4 = (size_t)NROWS * 319;

    float* w    = (float*)d_ws;
    float* d1   = w;
    float* d2   = d1 + n1;
    float* d3   = d2 + n2;
    float* d4   = d3 + n3;
    float* ca4  = d4 + n4;
    unsigned* bins  = (unsigned*)(ca4 + n4);
    unsigned* state = bins + 2048;
    float* sigp = (float*)(state + 2);
    const int n = (int)n4;  // 1,959,936

    hipLaunchKernelGGL(kernelA, dim3(NROWS), dim3(NT), 0, stream, x, d1, d2, d3, d4, ca4, bins, state);
    hipLaunchKernelGGL(khist, dim3(512), dim3(256), 0, stream, d4, n, bins, state, 21, 2047u, 0x00000000u);
    hipLaunchKernelGGL(kselect, dim3(1), dim3(256), 0, stream, bins, state, sigp, 21, 2048, 0);
    hipLaunchKernelGGL(khist, dim3(512), dim3(256), 0, stream, d4, n, bins, state, 10, 2047u, 0xFFE00000u);
    hipLaunchKernelGGL(kselect, dim3(1), dim3(256), 0, stream, bins, state, sigp, 10, 2048, 0);
    hipLaunchKernelGGL(khist, dim3(512), dim3(256), 0, stream, d4, n, bins, state, 0, 1023u, 0xFFFFFC00u);
    hipLaunchKernelGGL(kselect, dim3(1), dim3(256), 0, stream, bins, state, sigp, 0, 1024, 1);
    hipLaunchKernelGGL(kernelC, dim3(NROWS), dim3(NT), 0, stream, d1, d2, d3, d4, ca4, sigp, out);
}

// Round 8
// 413.474 us; speedup vs baseline: 1.0930x; 1.0069x over previous
//
#include <hip/hip_runtime.h>
#include <math.h>

#define NROWS 6144
#define LSIG  5000
#define NT    256

// db4 decomposition filters (natural order), hi[k] = (-1)^(k+1) lo[k]
#define DL0 (-0.010597401784997278f)
#define DL1 ( 0.032883011666982945f)
#define DL2 ( 0.030841381835986965f)
#define DL3 (-0.18703481171888114f)
#define DL4 (-0.02798376941698385f)
#define DL5 ( 0.6308807679295904f)
#define DL6 ( 0.7148465705525415f)
#define DL7 ( 0.23037781330885523f)
#define DH0 ( 0.010597401784997278f)
#define DH1 ( 0.032883011666982945f)
#define DH2 (-0.030841381835986965f)
#define DH3 (-0.18703481171888114f)
#define DH4 ( 0.02798376941698385f)
#define DH5 ( 0.6308807679295904f)
#define DH6 (-0.7148465705525415f)
#define DH7 ( 0.23037781330885523f)

// Forward DWT (edge path): ca[k] = sum_t xp[2k+t]*lo[7-t].
// xp index map (reflect pad 7,7 drop first): j=2k+t-6; i=|j|; if i>=L -> 2L-2-i
__device__ __forceinline__ void dwt_pair_edge(const float* __restrict__ src, int L, int k,
                                              float& a, float& b) {
    const float LO[8] = {DL0,DL1,DL2,DL3,DL4,DL5,DL6,DL7};
    const float HI[8] = {DH0,DH1,DH2,DH3,DH4,DH5,DH6,DH7};
    a = 0.f; b = 0.f;
    int base = 2*k - 6;
#pragma unroll
    for (int t = 0; t < 8; ++t) {
        int j = base + t;
        int i = (j < 0) ? -j : j;
        if (i >= L) i = 2*L - 2 - i;
        float v = src[i];
        a += v * LO[7-t];
        b += v * HI[7-t];
    }
}

// Interior fast path: valid when base >= 0 and base+7 <= L-1  (k>=3 && 2k+1<L)
// Lanes at stride-1 k -> LDS addresses at stride 2 floats -> free 2-way bank
// aliasing (m136). Loads widened to float2 (ds_read_b64): base = 2k-6 is even
// and every level base offset is even -> 8B aligned. Arithmetic expression is
// UNCHANGED (bit-identical values — any FP reorder here would propagate into
// the thresholded coefficients, a knife-edge vs the v<sigma comparison).
__device__ __forceinline__ void dwt_pair_int(const float* __restrict__ src, int k,
                                             float& a, float& b) {
    int base = 2*k - 6;
    const float2* s2 = (const float2*)(src + base);
    float2 p0 = s2[0], p1 = s2[1], p2 = s2[2], p3 = s2[3];
    float v0 = p0.x, v1 = p0.y, v2 = p1.x, v3 = p1.y;
    float v4 = p2.x, v5 = p2.y, v6 = p3.x, v7 = p3.y;
    a = v0*DL7 + v1*DL6 + v2*DL5 + v3*DL4 + v4*DL3 + v5*DL2 + v6*DL1 + v7*DL0;
    b = v0*DH7 + v1*DH6 + v2*DH5 + v3*DH4 + v4*DH3 + v5*DH2 + v6*DH1 + v7*DH0;
}

// Pair-form lowpass-only inverse: outputs o=2m (even) and o=2m+1 (odd) share ca[m..m+3].
// No bounds checks needed: for all our (O,C), (O-1)/2 + 3 < C holds.
__device__ __forceinline__ void idwt_lo_pair(const float* __restrict__ ca, int m,
                                             float& ev, float& od) {
    float c0 = ca[m], c1 = ca[m+1], c2 = ca[m+2], c3 = ca[m+3];
    ev = c0*DL1 + c1*DL3 + c2*DL5 + c3*DL7;
    od = c0*DL0 + c1*DL2 + c2*DL4 + c3*DL6;
}

// ---------------- Kernel A: baseline removal + forward 4-level DWT ----------------
// LDS ~40.3 KB -> 4 blocks/CU. Forward loops are per-output (stride-2 LDS).
// All pyramid level offsets EVEN so float2 LDS loads stay 8B-aligned.
// Block 0 zero-inits median bins/state (replaces kinit launch).
__global__ __launch_bounds__(NT, 4) void kernelA(const float* __restrict__ x,
                                                 float* __restrict__ g_d1, float* __restrict__ g_d2,
                                                 float* __restrict__ g_d3, float* __restrict__ g_d4,
                                                 float* __restrict__ g_ca4,
                                                 unsigned* __restrict__ bins,
                                                 unsigned* __restrict__ state) {
    __shared__ float sig0[5000];
    __shared__ float pyr[5040];    // levels 1..8 at even offsets: lens 2503,1255,631,319,163,85,46,26
    __shared__ float redm[9][4];
    __shared__ int depth_s;

    const int row = blockIdx.x;
    const int tid = threadIdx.x;

    if (row == 0) {
        for (int i = tid; i < 2048; i += NT) bins[i] = 0u;
        if (tid == 0) { state[0] = 0u; state[1] = 979967u; }  // k = (1959936-1)//2
    }

    {
        const float4* xr4 = (const float4*)(x + (size_t)row * LSIG);
        float4* s4 = (float4*)sig0;
        for (int i = tid; i < 1250; i += NT) s4[i] = xr4[i];
    }
    __syncthreads();

    const int lensA[10] = {5000, 2503, 1255, 631, 319, 163, 85, 46, 26, 16};
    const int offs[8]   = {0, 2504, 3760, 4392, 4712, 4876, 4962, 5008};  // all EVEN

    // ---- phase 1: pyramid; per-thread SSD accumulators (t=8 lowpass is discarded) ----
    float sp[9];
    const float* src = sig0;
#pragma unroll
    for (int t = 0; t < 9; ++t) {
        const int L   = lensA[t];
        const int Lo  = lensA[t + 1];
        const int kHi = (L - 2) >> 1;           // max k with 2k+1 <= L-1
        float* lp = pyr + ((t < 8) ? offs[t] : 0);
        float part = 0.f;
        for (int k = tid; k < Lo; k += NT) {
            float a, b;
            if (k >= 3 && k <= kHi) dwt_pair_int(src, k, a, b);
            else                    dwt_pair_edge(src, L, k, a, b);
            if (t < 8) lp[k] = a;
            part += b * b;
        }
        sp[t] = part;
        __syncthreads();
        src = lp;
    }

    // ---- one reduction for all 9 SSDs, then depth decision ----
#pragma unroll
    for (int t = 0; t < 9; ++t) {
        float p = sp[t];
#pragma unroll
        for (int o = 32; o; o >>= 1) p += __shfl_down(p, o, 64);
        if ((tid & 63) == 0) redm[t][tid >> 6] = p;
    }
    __syncthreads();
    if (tid == 0) {
        float ssds[9];
#pragma unroll
        for (int t = 0; t < 9; ++t) ssds[t] = redm[t][0] + redm[t][1] + redm[t][2] + redm[t][3];
        int dd = -1;
        for (int t = 2; t <= 8; ++t)
            if (dd < 0 && ssds[t - 2] > ssds[t - 1] && ssds[t - 1] < ssds[t]) dd = t;
        depth_s = (dd < 0) ? 8 : dd;
    }
    __syncthreads();
    const int d = depth_s;   // in [2,8]; sigs[d] = pyr + offs[d-1]

    // ---- baseline recon: (idwt_lo)^d of sigs[d], ping-pong in dead prefix; subtract ----
    // slot0 @pyr+0 (<=2503), slot1 @pyr+2504 (<=1255, ends 3759 < offs[2]=3760).
    const float* cur = pyr + offs[d - 1];
    for (int k = d - 1; k >= 1; --k) {
        const int ol = lensA[k];
        float* dst = (k & 1) ? pyr : (pyr + 2504);   // slot0 / slot1
        const int np = (ol + 1) >> 1;
        for (int m = tid; m < np; m += NT) {
            float ev, od;
            idwt_lo_pair(cur, m, ev, od);
            dst[2*m] = ev;
            if (2*m + 1 < ol) dst[2*m + 1] = od;
        }
        __syncthreads();
        cur = dst;
    }
    // final upsample (len 2503 -> 5000) fused with subtract; 2 pairs per iteration:
    // m, m+1 share c1..c3 -> 5 loads for 4 outputs; lane stride 2 floats = free.
    for (int q = tid; q < 1250; q += NT) {
        const int m = 2 * q;
        const float2* c2p = (const float2*)(cur + m);   // cur = slot0 (pyr+0), m even
        float2 ca01 = c2p[0], ca23 = c2p[1];
        float c0 = ca01.x, c1 = ca01.y, c2 = ca23.x, c3 = ca23.y, c4 = cur[m+4];
        float ev0 = c0*DL1 + c1*DL3 + c2*DL5 + c3*DL7;
        float od0 = c0*DL0 + c1*DL2 + c2*DL4 + c3*DL6;
        float ev1 = c1*DL1 + c2*DL3 + c3*DL5 + c4*DL7;
        float od1 = c1*DL0 + c2*DL2 + c3*DL4 + c4*DL6;
        sig0[2*m]     -= ev0;
        sig0[2*m + 1] -= od0;
        sig0[2*m + 2] -= ev1;
        sig0[2*m + 3] -= od1;
    }
    __syncthreads();

    // ---- phase 2: 4-level forward DWT of residual; details -> global, lp in pyr ----
    const int l2[5] = {5000, 2503, 1255, 631, 319};
    src = sig0;
#pragma unroll
    for (int lev = 0; lev < 4; ++lev) {
        const int L   = l2[lev];
        const int Lo  = l2[lev + 1];
        const int kHi = (L - 2) >> 1;
        float* lp = pyr + ((lev & 1) ? 2504 : 0);
        float* hg;
        if      (lev == 0) hg = g_d1 + (size_t)row * 2503;
        else if (lev == 1) hg = g_d2 + (size_t)row * 1255;
        else if (lev == 2) hg = g_d3 + (size_t)row * 631;
        else               hg = g_d4 + (size_t)row * 319;
        for (int k = tid; k < Lo; k += NT) {
            float a, b;
            if (k >= 3 && k <= kHi) dwt_pair_int(src, k, a, b);
            else                    dwt_pair_edge(src, L, k, a, b);
            lp[k] = a;
            hg[k] = b;
        }
        __syncthreads();
        src = lp;
    }
    float* cg = g_ca4 + (size_t)row * 319;
    for (int i = tid; i < 319; i += NT) cg[i] = pyr[2504 + i];
}

// ---------------- median radix-select kernels ----------------
__global__ void khist(const float* __restrict__ data, int n, unsigned* __restrict__ bins,
                      const unsigned* __restrict__ state, int shift, unsigned binmask,
                      unsigned prefmask) {
    __shared__ unsigned h[2048];
    const int nb = (int)binmask + 1;
    for (int i = threadIdx.x; i < nb; i += blockDim.x) h[i] = 0u;
    __syncthreads();
    const unsigned pref = state[0] & prefmask;
    const int stride = gridDim.x * blockDim.x;
    for (int i = blockIdx.x * blockDim.x + threadIdx.x; i < n; i += stride) {
        unsigned key = __float_as_uint(fabsf(data[i]));
        if ((key & prefmask) == pref) atomicAdd(&h[(key >> shift) & binmask], 1u);
    }
    __syncthreads();
    for (int i = threadIdx.x; i < nb; i += blockDim.x)
        if (h[i]) atomicAdd(&bins[i], h[i]);
}

// Radix-select step, LDS-accelerated (proven in R4: ~26 µs/launch -> ~4 µs).
// All 256 threads copy bins -> LDS and build chunk sums (parallel, before the
// barrier); thread 0 walks chunk sums + crossing chunk in LDS, reproducing the
// original cum/break semantics exactly (incl. the b = nbins-1 fall-through).
__global__ void kselect(unsigned* bins, unsigned* state,
                        float* sigma_out, int shift, int nbins, int final_pass) {
    __shared__ unsigned sb[2048];
    __shared__ unsigned cs[256];
    const int tid = threadIdx.x;
    const int CH  = nbins >> 8;              // bins per chunk: 8 (2048) or 4 (1024)
    unsigned sum = 0;
    for (int j = 0; j < CH; ++j) {
        unsigned v = bins[tid * CH + j];
        sb[tid * CH + j] = v;
        sum += v;
    }
    cs[tid] = sum;
    __syncthreads();
    if (tid == 0) {
        const unsigned krem = state[1];
        unsigned cum = 0;
        int ch = 0;
        for (; ch < 256; ++ch) {
            unsigned c = cs[ch];
            if (cum + c > krem) break;
            cum += c;
        }
        int b;
        if (ch == 256) {
            // no crossing: original loop falls through with b = nbins-1 and
            // cum = sum of bins[0..nbins-2]
            b = nbins - 1;
            cum -= sb[nbins - 1];
        } else {
            b = ch * CH;
            for (; b < nbins - 1; ++b) {
                unsigned c = sb[b];
                if (cum + c > krem) break;
                cum += c;
            }
        }
        unsigned prefix = state[0] | ((unsigned)b << shift);
        state[0] = prefix;
        state[1] = krem - cum;
        if (final_pass) *sigma_out = __uint_as_float(prefix) / 0.6745f;
    }
    __syncthreads();
    for (int i = tid; i < nbins; i += 256) bins[i] = 0u;
}

// ---------------- Kernel C: threshold + inverse DWT + normalize ----------------
// idwt exploits db4 QMF structure: DH{1,3,5,7} = DL{1,3,5,7}, DH{0,2,4,6} =
// -DL{0,2,4,6}  =>  ev = sum (c_i+e_i)*DL_odd, od = sum (c_i-e_i)*DL_even.
// Halves the idwt VALU work (26 ops vs 52 per 4 outputs). This runs AFTER the
// threshold decision, so the ~1-ulp reorder only perturbs the output (~1e-7,
// << 0.0156 tolerance); the v<sigma comparisons are bit-identical.
// TWO pairs per thread-iteration (lane stride 2 floats = free 2-way aliasing);
// float2 LDS loads (m = 2q even, A/B/Dd base-aligned). O % 4 == 0 all levels.
__global__ __launch_bounds__(NT, 4) void kernelC(const float* __restrict__ g_d1,
                                                 const float* __restrict__ g_d2,
                                                 const float* __restrict__ g_d3,
                                                 const float* __restrict__ g_d4,
                                                 const float* __restrict__ g_ca4,
                                                 const float* __restrict__ sigma_p,
                                                 float* __restrict__ out) {
    __shared__ float A[5000];
    __shared__ float B[2504];
    __shared__ float Dd[2504];
    __shared__ double redd[4][2];
    __shared__ float sg;

    const int row = blockIdx.x;
    const int tid = threadIdx.x;
    if (tid == 0) sg = *sigma_p;
    for (int i = tid; i < 319; i += NT) A[i] = g_ca4[(size_t)row * 319 + i];
    __syncthreads();
    const float sigma = sg;

    const int Cs[4] = {319, 631, 1255, 2503};
    const int Os[4] = {632, 1256, 2504, 5000};

#pragma unroll
    for (int s = 0; s < 4; ++s) {
        const int C = Cs[s];
        const int O = Os[s];
        const float* dg;
        if      (s == 0) dg = g_d4 + (size_t)row * 319;
        else if (s == 1) dg = g_d3 + (size_t)row * 631;
        else if (s == 2) dg = g_d2 + (size_t)row * 1255;
        else             dg = g_d1 + (size_t)row * 2503;
        const float* spb = (s & 1) ? B : A;   // 0:A 1:B 2:A 3:B
        float* dp        = (s & 1) ? A : B;
        for (int i = tid; i < C; i += NT) {
            float v = dg[i];
            Dd[i] = (v < sigma) ? 0.f : v;   // raw-value threshold, per reference
        }
        __syncthreads();
        const int nq = O >> 2;               // pair-pairs; O % 4 == 0 for all levels
        for (int q = tid; q < nq; q += NT) {
            const int m = 2 * q;
            const float2* cp = (const float2*)(spb + m);
            const float2* ep = (const float2*)(Dd + m);
            float2 cA = cp[0], cB = cp[1];
            float2 eA = ep[0], eB = ep[1];
            float c0 = cA.x, c1 = cA.y, c2 = cB.x, c3 = cB.y, c4 = spb[m+4];
            float e0 = eA.x, e1 = eA.y, e2 = eB.x, e3 = eB.y, e4 = Dd[m+4];
            float s0 = c0 + e0, s1 = c1 + e1, s2 = c2 + e2, s3 = c3 + e3, s4 = c4 + e4;
            float u0 = c0 - e0, u1 = c1 - e1, u2 = c2 - e2, u3 = c3 - e3, u4 = c4 - e4;
            float ev0 = s0*DL1 + s1*DL3 + s2*DL5 + s3*DL7;
            float od0 = u0*DL0 + u1*DL2 + u2*DL4 + u3*DL6;
            float ev1 = s1*DL1 + s2*DL3 + s3*DL5 + s4*DL7;
            float od1 = u1*DL0 + u2*DL2 + u3*DL4 + u4*DL6;
            dp[2*m]     = ev0;
            dp[2*m + 1] = od0;
            dp[2*m + 2] = ev1;
            dp[2*m + 3] = od1;
        }
        __syncthreads();
    }

    // normalize A[0..4999]: single-pass sum/sumsq in double, std(ddof=1), nan_to_num
    double s1 = 0.0, s2 = 0.0;
    for (int i = tid; i < 5000; i += NT) {
        double v = (double)A[i];
        s1 += v;
        s2 += v * v;
    }
#pragma unroll
    for (int o = 32; o; o >>= 1) {
        s1 += __shfl_down(s1, o, 64);
        s2 += __shfl_down(s2, o, 64);
    }
    if ((tid & 63) == 0) { redd[tid >> 6][0] = s1; redd[tid >> 6][1] = s2; }
    __syncthreads();
    double sum  = redd[0][0] + redd[1][0] + redd[2][0] + redd[3][0];
    double sumq = redd[0][1] + redd[1][1] + redd[2][1] + redd[3][1];
    double mean = sum / 5000.0;
    double var  = (sumq - sum * mean) / 4999.0;

    float meanf = (float)mean;
    float inv = 1.0f / (float)sqrt(var);
    float* orow = out + (size_t)row * 5000;
    for (int i = tid; i < 5000; i += NT) {
        float r = (A[i] - meanf) * inv;
        if (isnan(r)) r = 0.f;
        else if (isinf(r)) r = copysignf(3.4028234663852886e38f, r);
        orow[i] = r;
    }
}

extern "C" void kernel_launch(void* const* d_in, const int* in_sizes, int n_in,
                              void* d_out, int out_size, void* d_ws, size_t ws_size,
                              hipStream_t stream) {
    const float* x = (const float*)d_in[0];
    float* out = (float*)d_out;

    const size_t n1 = (size_t)NROWS * 2503;
    const size_t n2 = (size_t)NROWS * 1255;
    const size_t n3 = (size_t)NROWS * 631;
    const size_t n4 = (size_t)NROWS * 319;

    float* w    = (float*)d_ws;
    float* d1   = w;
    float* d2   = d1 + n1;
    float* d3   = d2 + n2;
    float* d4   = d3 + n3;
    float* ca4  = d4 + n4;
    unsigned* bins  = (unsigned*)(ca4 + n4);
    unsigned* state = bins + 2048;
    float* sigp = (float*)(state + 2);
    const int n = (int)n4;  // 1,959,936

    hipLaunchKernelGGL(kernelA, dim3(NROWS), dim3(NT), 0, stream, x, d1, d2, d3, d4, ca4, bins, state);
    hipLaunchKernelGGL(khist, dim3(512), dim3(256), 0, stream, d4, n, bins, state, 21, 2047u, 0x00000000u);
    hipLaunchKernelGGL(kselect, dim3(1), dim3(256), 0, stream, bins, state, sigp, 21, 2048, 0);
    hipLaunchKernelGGL(khist, dim3(512), dim3(256), 0, stream, d4, n, bins, state, 10, 2047u, 0xFFE00000u);
    hipLaunchKernelGGL(kselect, dim3(1), dim3(256), 0, stream, bins, state, sigp, 10, 2048, 0);
    hipLaunchKernelGGL(khist, dim3(512), dim3(256), 0, stream, d4, n, bins, state, 0, 1023u, 0xFFFFFC00u);
    hipLaunchKernelGGL(kselect, dim3(1), dim3(256), 0, stream, bins, state, sigp, 0, 1024, 1);
    hipLaunchKernelGGL(kernelC, dim3(NROWS), dim3(NT), 0, stream, d1, d2, d3, d4, ca4, sigp, out);
}

// Round 9
// 408.020 us; speedup vs baseline: 1.1076x; 1.0134x over previous
//
#include <hip/hip_runtime.h>
#include <math.h>

#define NROWS 6144
#define LSIG  5000
#define NT    256

// db4 decomposition filters (natural order), hi[k] = (-1)^(k+1) lo[k]
#define DL0 (-0.010597401784997278f)
#define DL1 ( 0.032883011666982945f)
#define DL2 ( 0.030841381835986965f)
#define DL3 (-0.18703481171888114f)
#define DL4 (-0.02798376941698385f)
#define DL5 ( 0.6308807679295904f)
#define DL6 ( 0.7148465705525415f)
#define DL7 ( 0.23037781330885523f)
#define DH0 ( 0.010597401784997278f)
#define DH1 ( 0.032883011666982945f)
#define DH2 (-0.030841381835986965f)
#define DH3 (-0.18703481171888114f)
#define DH4 ( 0.02798376941698385f)
#define DH5 ( 0.6308807679295904f)
#define DH6 (-0.7148465705525415f)
#define DH7 ( 0.23037781330885523f)

// Forward DWT (edge path): ca[k] = sum_t xp[2k+t]*lo[7-t].
// xp index map (reflect pad 7,7 drop first): j=2k+t-6; i=|j|; if i>=L -> 2L-2-i
__device__ __forceinline__ void dwt_pair_edge(const float* __restrict__ src, int L, int k,
                                              float& a, float& b) {
    const float LO[8] = {DL0,DL1,DL2,DL3,DL4,DL5,DL6,DL7};
    const float HI[8] = {DH0,DH1,DH2,DH3,DH4,DH5,DH6,DH7};
    a = 0.f; b = 0.f;
    int base = 2*k - 6;
#pragma unroll
    for (int t = 0; t < 8; ++t) {
        int j = base + t;
        int i = (j < 0) ? -j : j;
        if (i >= L) i = 2*L - 2 - i;
        float v = src[i];
        a += v * LO[7-t];
        b += v * HI[7-t];
    }
}

// Interior fast path: valid when base >= 0 and base+7 <= L-1  (k>=3 && 2k+1<L)
// Lanes at stride-1 k -> LDS addresses at stride 2 floats -> free 2-way bank
// aliasing (m136). float2 loads: base = 2k-6 even, level offsets even -> 8B
// aligned. Arithmetic UNCHANGED (bit-identical; coefficients feed v<sigma).
__device__ __forceinline__ void dwt_pair_int(const float* __restrict__ src, int k,
                                             float& a, float& b) {
    int base = 2*k - 6;
    const float2* s2 = (const float2*)(src + base);
    float2 p0 = s2[0], p1 = s2[1], p2 = s2[2], p3 = s2[3];
    float v0 = p0.x, v1 = p0.y, v2 = p1.x, v3 = p1.y;
    float v4 = p2.x, v5 = p2.y, v6 = p3.x, v7 = p3.y;
    a = v0*DL7 + v1*DL6 + v2*DL5 + v3*DL4 + v4*DL3 + v5*DL2 + v6*DL1 + v7*DL0;
    b = v0*DH7 + v1*DH6 + v2*DH5 + v3*DH4 + v4*DH3 + v5*DH2 + v6*DH1 + v7*DH0;
}

// Pair-form lowpass-only inverse: outputs o=2m (even) and o=2m+1 (odd) share ca[m..m+3].
// No bounds checks needed: for all our (O,C), (O-1)/2 + 3 < C holds.
// m = tid (lane stride 1) -> writes at stride 2 = FREE. Do NOT batch 2 pairs
// per lane: scalar writes at lane-stride-4 are an 8-way bank conflict
// (R6 read-side: 18.6M cycles; R4-R8 had the same mistake on the write side).
__device__ __forceinline__ void idwt_lo_pair(const float* __restrict__ ca, int m,
                                             float& ev, float& od) {
    float c0 = ca[m], c1 = ca[m+1], c2 = ca[m+2], c3 = ca[m+3];
    ev = c0*DL1 + c1*DL3 + c2*DL5 + c3*DL7;
    od = c0*DL0 + c1*DL2 + c2*DL4 + c3*DL6;
}

// ---------------- Kernel A: baseline removal + forward 4-level DWT ----------------
// LDS ~40.3 KB -> 4 blocks/CU. Forward loops per-output (stride-2 LDS). All
// pyramid level offsets EVEN for aligned float2. Block 0 zero-inits median
// bins/state/ticket (replaces kinit launch).
__global__ __launch_bounds__(NT, 4) void kernelA(const float* __restrict__ x,
                                                 float* __restrict__ g_d1, float* __restrict__ g_d2,
                                                 float* __restrict__ g_d3, float* __restrict__ g_d4,
                                                 float* __restrict__ g_ca4,
                                                 unsigned* __restrict__ bins,
                                                 unsigned* __restrict__ state) {
    __shared__ float sig0[5000];
    __shared__ float pyr[5040];    // levels 1..8 at even offsets: lens 2503,1255,631,319,163,85,46,26
    __shared__ float redm[9][4];
    __shared__ int depth_s;

    const int row = blockIdx.x;
    const int tid = threadIdx.x;

    if (row == 0) {
        for (int i = tid; i < 2048; i += NT) bins[i] = 0u;
        if (tid == 0) { state[0] = 0u; state[1] = 979967u; state[2] = 0u; }  // k = (1959936-1)//2; ticket
    }

    {
        const float4* xr4 = (const float4*)(x + (size_t)row * LSIG);
        float4* s4 = (float4*)sig0;
        for (int i = tid; i < 1250; i += NT) s4[i] = xr4[i];
    }
    __syncthreads();

    const int lensA[10] = {5000, 2503, 1255, 631, 319, 163, 85, 46, 26, 16};
    const int offs[8]   = {0, 2504, 3760, 4392, 4712, 4876, 4962, 5008};  // all EVEN

    // ---- phase 1: pyramid; per-thread SSD accumulators (t=8 lowpass is discarded) ----
    float sp[9];
    const float* src = sig0;
#pragma unroll
    for (int t = 0; t < 9; ++t) {
        const int L   = lensA[t];
        const int Lo  = lensA[t + 1];
        const int kHi = (L - 2) >> 1;           // max k with 2k+1 <= L-1
        float* lp = pyr + ((t < 8) ? offs[t] : 0);
        float part = 0.f;
        for (int k = tid; k < Lo; k += NT) {
            float a, b;
            if (k >= 3 && k <= kHi) dwt_pair_int(src, k, a, b);
            else                    dwt_pair_edge(src, L, k, a, b);
            if (t < 8) lp[k] = a;
            part += b * b;
        }
        sp[t] = part;
        __syncthreads();
        src = lp;
    }

    // ---- one reduction for all 9 SSDs, then depth decision ----
#pragma unroll
    for (int t = 0; t < 9; ++t) {
        float p = sp[t];
#pragma unroll
        for (int o = 32; o; o >>= 1) p += __shfl_down(p, o, 64);
        if ((tid & 63) == 0) redm[t][tid >> 6] = p;
    }
    __syncthreads();
    if (tid == 0) {
        float ssds[9];
#pragma unroll
        for (int t = 0; t < 9; ++t) ssds[t] = redm[t][0] + redm[t][1] + redm[t][2] + redm[t][3];
        int dd = -1;
        for (int t = 2; t <= 8; ++t)
            if (dd < 0 && ssds[t - 2] > ssds[t - 1] && ssds[t - 1] < ssds[t]) dd = t;
        depth_s = (dd < 0) ? 8 : dd;
    }
    __syncthreads();
    const int d = depth_s;   // in [2,8]; sigs[d] = pyr + offs[d-1]

    // ---- baseline recon: (idwt_lo)^d of sigs[d], ping-pong in dead prefix; subtract ----
    // slot0 @pyr+0 (<=2503), slot1 @pyr+2504 (<=1255, ends 3759 < offs[2]=3760).
    const float* cur = pyr + offs[d - 1];
    for (int k = d - 1; k >= 1; --k) {
        const int ol = lensA[k];
        float* dst = (k & 1) ? pyr : (pyr + 2504);   // slot0 / slot1
        const int np = (ol + 1) >> 1;
        for (int m = tid; m < np; m += NT) {
            float ev, od;
            idwt_lo_pair(cur, m, ev, od);
            dst[2*m] = ev;
            if (2*m + 1 < ol) dst[2*m + 1] = od;
        }
        __syncthreads();
        cur = dst;
    }
    // final upsample (len 2503 -> 5000) fused with subtract; per-pair (m = tid,
    // stride-1 reads / stride-2 writes = conflict-free). 2500 pairs.
    for (int m = tid; m < 2500; m += NT) {
        float ev, od;
        idwt_lo_pair(cur, m, ev, od);    // cur = slot0, len 2503
        sig0[2*m]     -= ev;
        sig0[2*m + 1] -= od;
    }
    __syncthreads();

    // ---- phase 2: 4-level forward DWT of residual; details -> global, lp in pyr ----
    const int l2[5] = {5000, 2503, 1255, 631, 319};
    src = sig0;
#pragma unroll
    for (int lev = 0; lev < 4; ++lev) {
        const int L   = l2[lev];
        const int Lo  = l2[lev + 1];
        const int kHi = (L - 2) >> 1;
        float* lp = pyr + ((lev & 1) ? 2504 : 0);
        float* hg;
        if      (lev == 0) hg = g_d1 + (size_t)row * 2503;
        else if (lev == 1) hg = g_d2 + (size_t)row * 1255;
        else if (lev == 2) hg = g_d3 + (size_t)row * 631;
        else               hg = g_d4 + (size_t)row * 319;
        for (int k = tid; k < Lo; k += NT) {
            float a, b;
            if (k >= 3 && k <= kHi) dwt_pair_int(src, k, a, b);
            else                    dwt_pair_edge(src, L, k, a, b);
            lp[k] = a;
            hg[k] = b;
        }
        __syncthreads();
        src = lp;
    }
    float* cg = g_ca4 + (size_t)row * 319;
    for (int i = tid; i < 319; i += NT) cg[i] = pyr[2504 + i];
}

// ------------- fused median radix pass: histogram + last-block select -------------
// Replaces khist+kselect pairs (7 middle launches -> 3). Each block histograms
// its strided float4 chunk into LDS, merges to global bins, then takes a ticket
// (atomicAdd after __threadfence). The LAST block re-reads bins via atomic-read
// (bullet-proof vs stale L1), runs the LDS-accelerated select (exact original
// cum/break semantics incl. b = nbins-1 fall-through), resets bins + ticket.
// state[0]=prefix, state[1]=krem, state[2]=ticket.
__global__ void khsel(const float4* __restrict__ data4, int n4,
                      unsigned* __restrict__ bins, unsigned* __restrict__ state,
                      float* __restrict__ sigma_out, int shift, unsigned binmask,
                      unsigned prefmask, int final_pass) {
    __shared__ unsigned h[2048];
    __shared__ unsigned cs[256];
    __shared__ int lastFlag;
    const int nb  = (int)binmask + 1;
    const int tid = threadIdx.x;

    for (int i = tid; i < nb; i += 256) h[i] = 0u;
    __syncthreads();
    const unsigned pref = state[0] & prefmask;
    const int stride = gridDim.x * 256;
    for (int i = blockIdx.x * 256 + tid; i < n4; i += stride) {
        float4 v = data4[i];
        unsigned k0 = __float_as_uint(fabsf(v.x));
        unsigned k1 = __float_as_uint(fabsf(v.y));
        unsigned k2 = __float_as_uint(fabsf(v.z));
        unsigned k3 = __float_as_uint(fabsf(v.w));
        if ((k0 & prefmask) == pref) atomicAdd(&h[(k0 >> shift) & binmask], 1u);
        if ((k1 & prefmask) == pref) atomicAdd(&h[(k1 >> shift) & binmask], 1u);
        if ((k2 & prefmask) == pref) atomicAdd(&h[(k2 >> shift) & binmask], 1u);
        if ((k3 & prefmask) == pref) atomicAdd(&h[(k3 >> shift) & binmask], 1u);
    }
    __syncthreads();
    for (int i = tid; i < nb; i += 256)
        if (h[i]) atomicAdd(&bins[i], h[i]);
    __syncthreads();

    if (tid == 0) {
        __threadfence();                                  // merges visible before ticket
        unsigned t = atomicAdd(&state[2], 1u);
        lastFlag = (t == gridDim.x - 1) ? 1 : 0;
    }
    __syncthreads();
    if (!lastFlag) return;

    // ---- last block: select ----
    const int CH = nb >> 8;                // 8 (2048 bins) or 4 (1024 bins)
    unsigned sum = 0;
    for (int j = 0; j < CH; ++j) {
        unsigned v = atomicAdd(&bins[tid * CH + j], 0u);  // coherent read
        h[tid * CH + j] = v;
        sum += v;
    }
    cs[tid] = sum;
    __syncthreads();
    if (tid == 0) {
        const unsigned krem = state[1];
        unsigned cum = 0;
        int ch = 0;
        for (; ch < 256; ++ch) {
            unsigned c = cs[ch];
            if (cum + c > krem) break;
            cum += c;
        }
        int b;
        if (ch == 256) {                   // no crossing: fall through to last bin
            b = nb - 1;
            cum -= h[nb - 1];
        } else {
            b = ch * CH;
            for (; b < nb - 1; ++b) {
                unsigned c = h[b];
                if (cum + c > krem) break;
                cum += c;
            }
        }
        unsigned prefix = state[0] | ((unsigned)b << shift);
        state[0] = prefix;
        state[1] = krem - cum;
        state[2] = 0u;                     // reset ticket for next pass
        if (final_pass) *sigma_out = __uint_as_float(prefix) / 0.6745f;
    }
    __syncthreads();
    for (int i = tid; i < nb; i += 256) bins[i] = 0u;
}

// ---------------- Kernel C: threshold + inverse DWT + normalize ----------------
// idwt uses db4 QMF structure: DH{1,3,5,7}=DL{1,3,5,7}, DH{0,2,4,6}=-DL{0,2,4,6}
//   => ev = sum (c_i+e_i)*DL_odd, od = sum (c_i-e_i)*DL_even  (half the FMAs).
// Runs AFTER the threshold decision -> ~1-ulp output perturbation only (passed
// R8 with absmax unchanged). Per-pair loop: m = tid -> stride-1 reads, stride-2
// writes = conflict-free (the R4-R8 pair-pair form wrote at lane-stride-4 =
// 8-way write conflict in the hottest loop).
__global__ __launch_bounds__(NT, 4) void kernelC(const float* __restrict__ g_d1,
                                                 const float* __restrict__ g_d2,
                                                 const float* __restrict__ g_d3,
                                                 const float* __restrict__ g_d4,
                                                 const float* __restrict__ g_ca4,
                                                 const float* __restrict__ sigma_p,
                                                 float* __restrict__ out) {
    __shared__ float A[5000];
    __shared__ float B[2504];
    __shared__ float Dd[2504];
    __shared__ double redd[4][2];
    __shared__ float sg;

    const int row = blockIdx.x;
    const int tid = threadIdx.x;
    if (tid == 0) sg = *sigma_p;
    for (int i = tid; i < 319; i += NT) A[i] = g_ca4[(size_t)row * 319 + i];
    __syncthreads();
    const float sigma = sg;

    const int Cs[4] = {319, 631, 1255, 2503};
    const int Os[4] = {632, 1256, 2504, 5000};

#pragma unroll
    for (int s = 0; s < 4; ++s) {
        const int C = Cs[s];
        const int O = Os[s];
        const float* dg;
        if      (s == 0) dg = g_d4 + (size_t)row * 319;
        else if (s == 1) dg = g_d3 + (size_t)row * 631;
        else if (s == 2) dg = g_d2 + (size_t)row * 1255;
        else             dg = g_d1 + (size_t)row * 2503;
        const float* spb = (s & 1) ? B : A;   // 0:A 1:B 2:A 3:B
        float* dp        = (s & 1) ? A : B;
        for (int i = tid; i < C; i += NT) {
            float v = dg[i];
            Dd[i] = (v < sigma) ? 0.f : v;   // raw-value threshold, per reference
        }
        __syncthreads();
        const int np = O >> 1;               // O always even; max m+3 = C-1 each level
        for (int m = tid; m < np; m += NT) {
            float c0 = spb[m], c1 = spb[m+1], c2 = spb[m+2], c3 = spb[m+3];
            float e0 = Dd[m],  e1 = Dd[m+1],  e2 = Dd[m+2],  e3 = Dd[m+3];
            float s0 = c0 + e0, s1 = c1 + e1, s2 = c2 + e2, s3 = c3 + e3;
            float u0 = c0 - e0, u1 = c1 - e1, u2 = c2 - e2, u3 = c3 - e3;
            dp[2*m]     = s0*DL1 + s1*DL3 + s2*DL5 + s3*DL7;
            dp[2*m + 1] = u0*DL0 + u1*DL2 + u2*DL4 + u3*DL6;
        }
        __syncthreads();
    }

    // normalize A[0..4999]: single-pass sum/sumsq in double, std(ddof=1), nan_to_num
    double s1 = 0.0, s2 = 0.0;
    for (int i = tid; i < 5000; i += NT) {
        double v = (double)A[i];
        s1 += v;
        s2 += v * v;
    }
#pragma unroll
    for (int o = 32; o; o >>= 1) {
        s1 += __shfl_down(s1, o, 64);
        s2 += __shfl_down(s2, o, 64);
    }
    if ((tid & 63) == 0) { redd[tid >> 6][0] = s1; redd[tid >> 6][1] = s2; }
    __syncthreads();
    double sum  = redd[0][0] + redd[1][0] + redd[2][0] + redd[3][0];
    double sumq = redd[0][1] + redd[1][1] + redd[2][1] + redd[3][1];
    double mean = sum / 5000.0;
    double var  = (sumq - sum * mean) / 4999.0;

    float meanf = (float)mean;
    float inv = 1.0f / (float)sqrt(var);
    float* orow = out + (size_t)row * 5000;
    for (int i = tid; i < 5000; i += NT) {
        float r = (A[i] - meanf) * inv;
        if (isnan(r)) r = 0.f;
        else if (isinf(r)) r = copysignf(3.4028234663852886e38f, r);
        orow[i] = r;
    }
}

extern "C" void kernel_launch(void* const* d_in, const int* in_sizes, int n_in,
                              void* d_out, int out_size, void* d_ws, size_t ws_size,
                              hipStream_t stream) {
    const float* x = (const float*)d_in[0];
    float* out = (float*)d_out;

    const size_t n1 = (size_t)NROWS * 2503;
    const size_t n2 = (size_t)NROWS * 1255;
    const size_t n3 = (size_t)NROWS * 631;
    const size_t n4 = (size_t)NROWS * 319;

    float* w    = (float*)d_ws;
    float* d1   = w;
    float* d2   = d1 + n1;
    float* d3   = d2 + n2;
    float* d4   = d3 + n3;
    float* ca4  = d4 + n4;
    unsigned* bins  = (unsigned*)(ca4 + n4);
    unsigned* state = bins + 2048;   // [0]=prefix [1]=krem [2]=ticket
    float* sigp = (float*)(state + 4);
    const int nq4 = (int)(n4 / 4);   // 489,984 float4s (n4 % 4 == 0)

    hipLaunchKernelGGL(kernelA, dim3(NROWS), dim3(NT), 0, stream, x, d1, d2, d3, d4, ca4, bins, state);
    hipLaunchKernelGGL(khsel, dim3(256), dim3(256), 0, stream, (const float4*)d4, nq4,
                       bins, state, sigp, 21, 2047u, 0x00000000u, 0);
    hipLaunchKernelGGL(khsel, dim3(256), dim3(256), 0, stream, (const float4*)d4, nq4,
                       bins, state, sigp, 10, 2047u, 0xFFE00000u, 0);
    hipLaunchKernelGGL(khsel, dim3(256), dim3(256), 0, stream, (const float4*)d4, nq4,
                       bins, state, sigp, 0, 1023u, 0xFFFFFC00u, 1);
    hipLaunchKernelGGL(kernelC, dim3(NROWS), dim3(NT), 0, stream, d1, d2, d3, d4, ca4, sigp, out);
}